// Round 2
// baseline (7858.150 us; speedup 1.0000x reference)
//
#include <hip/hip_runtime.h>
#include <hip/hip_bf16.h>

// Problem constants (fixed by the reference)
#define LL 16
#define BB 2
#define NN 1024
#define CC 512
#define HH 16
#define FF 1024
#define VV 32768
#define MM (BB * NN)   // 2048 token rows
#define DK 32          // head dim

typedef __bf16 bf16x8 __attribute__((ext_vector_type(8)));
typedef float  f32x4  __attribute__((ext_vector_type(4)));

// ---------------------------------------------------------------------------
// Embedding: x[m,c] = tok_emb[ids[m],c] + pos_emb[m%N,c]
// ---------------------------------------------------------------------------
__global__ __launch_bounds__(256) void embed_kernel(
    const int* __restrict__ ids, const float* __restrict__ tok,
    const float* __restrict__ pos, float* __restrict__ x)
{
  int i  = blockIdx.x * 256 + threadIdx.x;      // over M*C/4 float4s
  int c4 = (i & (CC / 4 - 1)) * 4;              // C/4 = 128
  int m  = i >> 7;
  int n  = m & (NN - 1);
  int id = ids[m];
  float4 t = *(const float4*)(tok + (size_t)id * CC + c4);
  float4 p = *(const float4*)(pos + (size_t)n * CC + c4);
  float4 r; r.x = t.x + p.x; r.y = t.y + p.y; r.z = t.z + p.z; r.w = t.w + p.w;
  *(float4*)(x + (size_t)m * CC + c4) = r;
}

// ---------------------------------------------------------------------------
// LayerNorm over C=512. One 64-lane wave per row, 4 rows per 256-thr block.
// ---------------------------------------------------------------------------
__global__ __launch_bounds__(256) void ln_kernel(
    const float* __restrict__ x, const float* __restrict__ g,
    const float* __restrict__ b, float* __restrict__ out)
{
  int row  = blockIdx.x * 4 + (threadIdx.x >> 6);
  int lane = threadIdx.x & 63;
  const float* xr = x + (size_t)row * CC;
  float4 v0 = *(const float4*)(xr + lane * 4);
  float4 v1 = *(const float4*)(xr + 256 + lane * 4);
  float s = v0.x + v0.y + v0.z + v0.w + v1.x + v1.y + v1.z + v1.w;
  #pragma unroll
  for (int o = 32; o; o >>= 1) s += __shfl_xor(s, o, 64);
  float mean = s * (1.0f / CC);
  float q =
      (v0.x-mean)*(v0.x-mean) + (v0.y-mean)*(v0.y-mean) +
      (v0.z-mean)*(v0.z-mean) + (v0.w-mean)*(v0.w-mean) +
      (v1.x-mean)*(v1.x-mean) + (v1.y-mean)*(v1.y-mean) +
      (v1.z-mean)*(v1.z-mean) + (v1.w-mean)*(v1.w-mean);
  #pragma unroll
  for (int o = 32; o; o >>= 1) q += __shfl_xor(q, o, 64);
  float r = rsqrtf(q * (1.0f / CC) + 1e-5f);

  float4 g0 = *(const float4*)(g + lane * 4);
  float4 g1 = *(const float4*)(g + 256 + lane * 4);
  float4 b0 = *(const float4*)(b + lane * 4);
  float4 b1 = *(const float4*)(b + 256 + lane * 4);
  float4 o0, o1;
  o0.x = (v0.x - mean) * r * g0.x + b0.x;
  o0.y = (v0.y - mean) * r * g0.y + b0.y;
  o0.z = (v0.z - mean) * r * g0.z + b0.z;
  o0.w = (v0.w - mean) * r * g0.w + b0.w;
  o1.x = (v1.x - mean) * r * g1.x + b1.x;
  o1.y = (v1.y - mean) * r * g1.y + b1.y;
  o1.z = (v1.z - mean) * r * g1.z + b1.z;
  o1.w = (v1.w - mean) * r * g1.w + b1.w;
  float* orow = out + (size_t)row * CC;
  *(float4*)(orow + lane * 4)       = o0;
  *(float4*)(orow + 256 + lane * 4) = o1;
}

// ---------------------------------------------------------------------------
// Split-bf16 MFMA GEMM: C[M,Nc] = A[M,K] @ B (+bias)(+gelu)(+resid), fp32 io.
// Each fp32 operand is split a = hi + lo (both bf16); D accumulates
// Ah*Bh + Ah*Bl + Al*Bh in fp32 (error ~2^-16 per product).
// Tile 128x128, BK=32, 256 threads = 4 waves in 2x2, each wave 64x64 out.
// LDS layout: k-chunk-major planes [4][128][8] bf16 -> linear ds_read_b128
// per 16-lane group (conflict-free), no swizzle needed.
// BT=true: B stored [Nc,K] row-major (logits GEMM vs tok_emb).
// ---------------------------------------------------------------------------
template <bool BT, bool HASB, bool RES, bool GELU>
__global__ __launch_bounds__(256, 2) void gemm_mfma(
    const float* __restrict__ A, const float* __restrict__ Bm,
    const float* __restrict__ bias, const float* __restrict__ resid,
    float* __restrict__ Cout, int M, int Nc, int K)
{
  __shared__ __align__(16) __bf16 Ah[4 * 128 * 8];
  __shared__ __align__(16) __bf16 Al[4 * 128 * 8];
  __shared__ __align__(16) __bf16 Bh[4 * 128 * 8];
  __shared__ __align__(16) __bf16 Bl[4 * 128 * 8];

  const int t    = threadIdx.x;
  const int lane = t & 63;
  const int wid  = t >> 6;
  const int wr   = wid >> 1;      // wave row (0/1)
  const int wc   = wid & 1;       // wave col (0/1)
  const int fr   = lane & 15;     // row within fragment
  const int fc   = lane >> 4;     // k-chunk 0..3

  const int m0 = blockIdx.y * 128, n0 = blockIdx.x * 128;

  // staging coords
  const int arow = t >> 1;              // 0..127
  const int akb  = (t & 1) * 16;        // k offset 0/16
  const int bn   = t & 127;             // col for normal-B staging
  const int bkh  = (t >> 7) * 16;       // k half for normal-B staging

  f32x4 acc[4][4] = {};

  for (int k0 = 0; k0 < K; k0 += 32) {
    __syncthreads();
    // ---- stage A (rows m0..m0+127, k0..k0+31), convert to hi/lo bf16
    {
      const float* ap = A + (size_t)(m0 + arow) * K + k0 + akb;
      float fv[16];
      *(float4*)(fv + 0)  = *(const float4*)(ap + 0);
      *(float4*)(fv + 4)  = *(const float4*)(ap + 4);
      *(float4*)(fv + 8)  = *(const float4*)(ap + 8);
      *(float4*)(fv + 12) = *(const float4*)(ap + 12);
      #pragma unroll
      for (int w = 0; w < 2; ++w) {
        bf16x8 hv, lv;
        #pragma unroll
        for (int e = 0; e < 8; ++e) {
          float f = fv[w * 8 + e];
          __bf16 hh = (__bf16)f;
          hv[e] = hh;
          lv[e] = (__bf16)(f - (float)hh);
        }
        int c = (akb >> 3) + w;                 // k-chunk 0..3
        *(bf16x8*)&Ah[(c * 128 + arow) * 8] = hv;
        *(bf16x8*)&Al[(c * 128 + arow) * 8] = lv;
      }
    }
    // ---- stage B transposed into [chunk][n][8]
    if (BT) {
      const float* bp = Bm + (size_t)(n0 + arow) * K + k0 + akb;
      float fv[16];
      *(float4*)(fv + 0)  = *(const float4*)(bp + 0);
      *(float4*)(fv + 4)  = *(const float4*)(bp + 4);
      *(float4*)(fv + 8)  = *(const float4*)(bp + 8);
      *(float4*)(fv + 12) = *(const float4*)(bp + 12);
      #pragma unroll
      for (int w = 0; w < 2; ++w) {
        bf16x8 hv, lv;
        #pragma unroll
        for (int e = 0; e < 8; ++e) {
          float f = fv[w * 8 + e];
          __bf16 hh = (__bf16)f;
          hv[e] = hh;
          lv[e] = (__bf16)(f - (float)hh);
        }
        int c = (akb >> 3) + w;
        *(bf16x8*)&Bh[(c * 128 + arow) * 8] = hv;
        *(bf16x8*)&Bl[(c * 128 + arow) * 8] = lv;
      }
    } else {
      float fv[16];
      #pragma unroll
      for (int kk = 0; kk < 16; ++kk)
        fv[kk] = Bm[(size_t)(k0 + bkh + kk) * Nc + n0 + bn];
      #pragma unroll
      for (int w = 0; w < 2; ++w) {
        bf16x8 hv, lv;
        #pragma unroll
        for (int e = 0; e < 8; ++e) {
          float f = fv[w * 8 + e];
          __bf16 hh = (__bf16)f;
          hv[e] = hh;
          lv[e] = (__bf16)(f - (float)hh);
        }
        int c = (bkh >> 3) + w;
        *(bf16x8*)&Bh[(c * 128 + bn) * 8] = hv;
        *(bf16x8*)&Bl[(c * 128 + bn) * 8] = lv;
      }
    }
    __syncthreads();

    // ---- fragments + MFMA
    bf16x8 ahv[4], alv[4], bhv[4], blv[4];
    #pragma unroll
    for (int f = 0; f < 4; ++f) {
      int ar = wr * 64 + f * 16 + fr;
      ahv[f] = *(const bf16x8*)&Ah[(fc * 128 + ar) * 8];
      alv[f] = *(const bf16x8*)&Al[(fc * 128 + ar) * 8];
      int br = wc * 64 + f * 16 + fr;
      bhv[f] = *(const bf16x8*)&Bh[(fc * 128 + br) * 8];
      blv[f] = *(const bf16x8*)&Bl[(fc * 128 + br) * 8];
    }
    #pragma unroll
    for (int mi = 0; mi < 4; ++mi)
      #pragma unroll
      for (int nj = 0; nj < 4; ++nj) {
        acc[mi][nj] = __builtin_amdgcn_mfma_f32_16x16x32_bf16(
            ahv[mi], bhv[nj], acc[mi][nj], 0, 0, 0);
        acc[mi][nj] = __builtin_amdgcn_mfma_f32_16x16x32_bf16(
            ahv[mi], blv[nj], acc[mi][nj], 0, 0, 0);
        acc[mi][nj] = __builtin_amdgcn_mfma_f32_16x16x32_bf16(
            alv[mi], bhv[nj], acc[mi][nj], 0, 0, 0);
      }
  }

  // ---- epilogue: C/D map col=lane&15, row=(lane>>4)*4+r (m89-verified)
  #pragma unroll
  for (int mi = 0; mi < 4; ++mi) {
    #pragma unroll
    for (int nj = 0; nj < 4; ++nj) {
      int col = n0 + wc * 64 + nj * 16 + fr;
      float bv = HASB ? bias[col] : 0.0f;
      #pragma unroll
      for (int r = 0; r < 4; ++r) {
        int row = m0 + wr * 64 + mi * 16 + fc * 4 + r;
        float val = acc[mi][nj][r] + bv;
        if (GELU) val = 0.5f * val * (1.0f + erff(val * 0.70710678118654752f));
        if (RES)  val += resid[(size_t)row * Nc + col];
        Cout[(size_t)row * Nc + col] = val;
      }
    }
  }
}

// ---------------------------------------------------------------------------
// Causal flash attention, fp32. One wave per (b, h, 64-row q-tile).
// ---------------------------------------------------------------------------
__global__ __launch_bounds__(64) void attn_kernel(
    const float* __restrict__ qkv, float* __restrict__ o)
{
  __shared__ float Ks[64][DK];
  __shared__ float Vs[64][DK];
  __shared__ float Sc[64][64];   // Sc[key][lane]
  const int lane = threadIdx.x;
  const int qt = blockIdx.x & 15;        // N/64 = 16 q-tiles
  const int bh = blockIdx.x >> 4;
  const int h  = bh & 15;
  const int b  = bh >> 4;
  const int qn = qt * 64 + lane;
  const size_t mrow = (size_t)(b * NN + qn);
  const float scale = 0.17677669529663687f;  // 1/sqrt(32)

  float q[DK];
  const float* qp = qkv + mrow * (3 * CC) + h * DK;
  #pragma unroll
  for (int i = 0; i < 8; ++i) {
    float4 t = *(const float4*)(qp + i * 4);
    q[i * 4] = t.x; q[i * 4 + 1] = t.y; q[i * 4 + 2] = t.z; q[i * 4 + 3] = t.w;
  }

  float acc[DK] = {};
  float mi = -1e30f, li = 0.0f;

  for (int kt = 0; kt <= qt; ++kt) {
    __syncthreads();
    #pragma unroll
    for (int i = 0; i < 8; ++i) {
      int idx = i * 64 + lane;
      int r = idx >> 3;
      int c4 = (idx & 7) * 4;
      const float* kp =
          qkv + (size_t)(b * NN + kt * 64 + r) * (3 * CC) + h * DK + c4;
      *(float4*)&Ks[r][c4] = *(const float4*)(kp + CC);
      *(float4*)&Vs[r][c4] = *(const float4*)(kp + 2 * CC);
    }
    __syncthreads();

    const int kbase = kt * 64;
    float tmax = -1e30f;
    for (int j = 0; j < 64; ++j) {
      float d0 = 0, d1 = 0, d2 = 0, d3 = 0;
      #pragma unroll
      for (int c = 0; c < DK; c += 4) {
        d0 = fmaf(q[c + 0], Ks[j][c + 0], d0);
        d1 = fmaf(q[c + 1], Ks[j][c + 1], d1);
        d2 = fmaf(q[c + 2], Ks[j][c + 2], d2);
        d3 = fmaf(q[c + 3], Ks[j][c + 3], d3);
      }
      float d = ((d0 + d1) + (d2 + d3)) * scale;
      d = (kbase + j <= qn) ? d : -1e30f;
      Sc[j][lane] = d;
      tmax = fmaxf(tmax, d);
    }

    float mnew = fmaxf(mi, tmax);
    float csc = expf(mi - mnew);
    li *= csc;
    #pragma unroll
    for (int c = 0; c < DK; ++c) acc[c] *= csc;
    float ps = 0.0f;
    for (int j = 0; j < 64; ++j) {
      float p = expf(Sc[j][lane] - mnew);
      ps += p;
      #pragma unroll
      for (int c = 0; c < DK; ++c) acc[c] = fmaf(p, Vs[j][c], acc[c]);
    }
    li += ps;
    mi = mnew;
  }

  float inv = 1.0f / li;
  float* op = o + mrow * CC + h * DK;
  #pragma unroll
  for (int i = 0; i < 8; ++i) {
    float4 t;
    t.x = acc[i * 4] * inv;     t.y = acc[i * 4 + 1] * inv;
    t.z = acc[i * 4 + 2] * inv; t.w = acc[i * 4 + 3] * inv;
    *(float4*)(op + i * 4) = t;
  }
}

// ---------------------------------------------------------------------------
__global__ __launch_bounds__(256) void tgt_kernel(
    const int* __restrict__ t, float* __restrict__ out)
{
  int i = blockIdx.x * 256 + threadIdx.x;
  out[i] = (float)t[i];
}

// ---------------------------------------------------------------------------
extern "C" void kernel_launch(void* const* d_in, const int* in_sizes, int n_in,
                              void* d_out, int out_size, void* d_ws,
                              size_t ws_size, hipStream_t stream)
{
  (void)in_sizes; (void)n_in; (void)out_size; (void)ws_size;
  const int*   ids  = (const int*)d_in[0];
  const int*   tgt  = (const int*)d_in[1];
  const float* tok  = (const float*)d_in[2];
  const float* pos  = (const float*)d_in[3];
  const float* Wqkv = (const float*)d_in[4];
  const float* bqkv = (const float*)d_in[5];
  const float* Wo   = (const float*)d_in[6];
  const float* bo   = (const float*)d_in[7];
  const float* ln1g = (const float*)d_in[8];
  const float* ln1b = (const float*)d_in[9];
  const float* W1   = (const float*)d_in[10];
  const float* b1   = (const float*)d_in[11];
  const float* W2   = (const float*)d_in[12];
  const float* b2   = (const float*)d_in[13];
  const float* ln2g = (const float*)d_in[14];
  const float* ln2b = (const float*)d_in[15];
  const float* lnfg = (const float*)d_in[16];
  const float* lnfb = (const float*)d_in[17];

  // workspace layout (floats): x 1M | h 1M | qkv 3M | o 1M | f1 2M = 32 MB
  float* x   = (float*)d_ws;
  float* h   = x + (size_t)MM * CC;
  float* qkv = h + (size_t)MM * CC;
  float* o   = qkv + (size_t)MM * 3 * CC;
  float* f1  = o + (size_t)MM * CC;

  float* logits  = (float*)d_out;
  float* tgt_out = logits + (size_t)MM * VV;

  embed_kernel<<<MM * CC / 4 / 256, 256, 0, stream>>>(ids, tok, pos, x);

  for (int l = 0; l < LL; ++l) {
    ln_kernel<<<MM / 4, 256, 0, stream>>>(x, ln1g + l * CC, ln1b + l * CC, h);
    gemm_mfma<false, true, false, false>
        <<<dim3(3 * CC / 128, MM / 128), 256, 0, stream>>>(
            h, Wqkv + (size_t)l * CC * 3 * CC, bqkv + (size_t)l * 3 * CC,
            nullptr, qkv, MM, 3 * CC, CC);
    attn_kernel<<<BB * HH * (NN / 64), 64, 0, stream>>>(qkv, o);
    gemm_mfma<false, true, true, false>
        <<<dim3(CC / 128, MM / 128), 256, 0, stream>>>(
            o, Wo + (size_t)l * CC * CC, bo + (size_t)l * CC, x, x, MM, CC, CC);
    ln_kernel<<<MM / 4, 256, 0, stream>>>(x, ln2g + l * CC, ln2b + l * CC, h);
    gemm_mfma<false, true, false, true>
        <<<dim3(FF / 128, MM / 128), 256, 0, stream>>>(
            h, W1 + (size_t)l * CC * FF, b1 + (size_t)l * FF, nullptr, f1,
            MM, FF, CC);
    gemm_mfma<false, true, true, false>
        <<<dim3(CC / 128, MM / 128), 256, 0, stream>>>(
            f1, W2 + (size_t)l * FF * CC, b2 + (size_t)l * CC, x, x, MM, CC, FF);
  }

  ln_kernel<<<MM / 4, 256, 0, stream>>>(x, lnfg, lnfb, h);
  gemm_mfma<true, false, false, false>
      <<<dim3(VV / 128, MM / 128), 256, 0, stream>>>(
          h, tok, nullptr, nullptr, logits, MM, VV, CC);
  tgt_kernel<<<MM / 256, 256, 0, stream>>>(tgt, tgt_out);
}